// Round 1
// baseline (6472.453 us; speedup 1.0000x reference)
//
#include <hip/hip_runtime.h>
#include <cstdint>
#include <cstddef>

#define Bsz 16
#define Tt  512
#define Kk  8
#define NI  256
#define UN  256
#define G4  1024   // 4*UN

__global__ void init_state_kernel(float* s, int n) {
    int i = blockIdx.x * blockDim.x + threadIdx.x;
    if (i < n) s[i] = 0.0f;
}

// xw[t'][b][k][j] = bias[k][j] + sum_i x[b][t0+t'][k][i] * W[k][i][j]
// row r = t'*16 + b  (so b = r&15, t' = r>>4)
// grid: (G4/128, TC*16/128, Kk), block 256
__global__ __launch_bounds__(256) void xw_gemm(const float* __restrict__ x,
                                               const float* __restrict__ W,
                                               const float* __restrict__ bias,
                                               float* __restrict__ xw, int t0) {
    __shared__ __align__(16) float At[16][132];  // [kk][row], pad 132: b128-aligned rows
    __shared__ __align__(16) float Bt[16][132];  // [kk][col]

    const int k  = blockIdx.z;
    const int C0 = blockIdx.x * 128;
    const int R0 = blockIdx.y * 128;
    const int tid = threadIdx.x;
    const int tx = tid & 15, ty = tid >> 4;

    float acc[8][8];
#pragma unroll
    for (int i = 0; i < 8; i++)
#pragma unroll
        for (int j = 0; j < 8; j++) acc[i][j] = 0.0f;

    const int lakk = tid & 15, larl = tid >> 4;   // A load: i-offset, row
    const int lbc  = tid & 127, lbk = tid >> 7;   // B load: col, kk base

    for (int kt = 0; kt < NI; kt += 16) {
#pragma unroll
        for (int ps = 0; ps < 8; ps++) {          // A tile: 128 rows x 16 i
            int rloc = larl + ps * 16;
            int r = R0 + rloc;
            int b = r & 15, tp = r >> 4;
            At[lakk][rloc] = x[(((size_t)b * Tt + (t0 + tp)) * Kk + k) * NI + kt + lakk];
        }
#pragma unroll
        for (int ps = 0; ps < 8; ps++) {          // B tile: 16 kk x 128 cols
            int kkr = lbk + ps * 2;
            Bt[kkr][lbc] = W[((size_t)k * NI + kt + kkr) * G4 + C0 + lbc];
        }
        __syncthreads();
#pragma unroll
        for (int kk = 0; kk < 16; kk++) {
            const float4* Ar = (const float4*)&At[kk][ty * 8];
            const float4* Br = (const float4*)&Bt[kk][tx * 8];
            float4 a0 = Ar[0], a1 = Ar[1];
            float4 b0 = Br[0], b1 = Br[1];
            float a[8] = {a0.x, a0.y, a0.z, a0.w, a1.x, a1.y, a1.z, a1.w};
            float bb[8] = {b0.x, b0.y, b0.z, b0.w, b1.x, b1.y, b1.z, b1.w};
#pragma unroll
            for (int i = 0; i < 8; i++)
#pragma unroll
                for (int j = 0; j < 8; j++)
                    acc[i][j] = fmaf(a[i], bb[j], acc[i][j]);
        }
        __syncthreads();
    }
    // epilogue: add bias, write xw
    float bv[8];
#pragma unroll
    for (int j = 0; j < 8; j++) bv[j] = bias[(size_t)k * G4 + C0 + tx * 8 + j];
#pragma unroll
    for (int i = 0; i < 8; i++) {
        int r = R0 + ty * 8 + i;
        int b = r & 15, tp = r >> 4;
        float* op = xw + ((size_t)tp * 128 + b * 8 + k) * G4 + C0 + tx * 8;
#pragma unroll
        for (int j = 0; j < 8; j++) op[j] = acc[i][j] + bv[j];
    }
}

__device__ __forceinline__ float hsig(float z) {
    return fminf(1.0f, fmaxf(0.0f, fmaf(z, 0.2f, 0.5f)));
}

// Recurrent phase. grid 64 wgs: k = bid&7 (-> XCD k under round-robin), bpair = bid>>3.
// Each wg handles batches (bpair, bpair+8); thread u owns unit u of both.
__global__ __launch_bounds__(256) void lstm_seq(const float* __restrict__ xw,
                                                const float* __restrict__ U,
                                                float* __restrict__ out,
                                                float* __restrict__ hst,
                                                float* __restrict__ cst,
                                                int t0, int TC) {
    const int u  = threadIdx.x;
    const int k  = blockIdx.x & 7;
    const int b0 = blockIdx.x >> 3;
    const int b1 = b0 + 8;
    const int p0 = b0 * 8 + k, p1 = b1 * 8 + k;

    __shared__ __align__(16) float h0s[UN];
    __shared__ __align__(16) float h1s[UN];

    const float* __restrict__ Uk = U + (size_t)k * NI * G4 + u;

    float c0 = cst[p0 * UN + u];
    float c1 = cst[p1 * UN + u];
    h0s[u] = hst[p0 * UN + u];
    h1s[u] = hst[p1 * UN + u];
    __syncthreads();

    for (int t = 0; t < TC; t++) {
        const float* xp0 = xw + ((size_t)t * 128 + p0) * G4 + u;
        const float* xp1 = xw + ((size_t)t * 128 + p1) * G4 + u;
        float za0 = xp0[0], zi0 = xp0[256], zf0 = xp0[512], zo0 = xp0[768];
        float za1 = xp1[0], zi1 = xp1[256], zf1 = xp1[512], zo1 = xp1[768];

#pragma unroll 8
        for (int i = 0; i < NI; i += 4) {
            float4 ha4 = *(const float4*)&h0s[i];
            float4 hb4 = *(const float4*)&h1s[i];
            const float ha[4] = {ha4.x, ha4.y, ha4.z, ha4.w};
            const float hb[4] = {hb4.x, hb4.y, hb4.z, hb4.w};
#pragma unroll
            for (int d = 0; d < 4; d++) {
                const float* up = Uk + (size_t)(i + d) * G4;
                float u0 = up[0], u1 = up[256], u2 = up[512], u3 = up[768];
                za0 = fmaf(ha[d], u0, za0); zi0 = fmaf(ha[d], u1, zi0);
                zf0 = fmaf(ha[d], u2, zf0); zo0 = fmaf(ha[d], u3, zo0);
                za1 = fmaf(hb[d], u0, za1); zi1 = fmaf(hb[d], u1, zi1);
                zf1 = fmaf(hb[d], u2, zf1); zo1 = fmaf(hb[d], u3, zo1);
            }
        }

        float a0 = tanhf(za0), a1 = tanhf(za1);
        float i0 = hsig(zi0),  i1 = hsig(zi1);
        float f0 = hsig(zf0),  f1 = hsig(zf1);
        float o0 = hsig(zo0),  o1 = hsig(zo1);
        c0 = a0 * i0 + f0 * c0;
        c1 = a1 * i1 + f1 * c1;
        float hn0 = o0 * tanhf(c0);
        float hn1 = o1 * tanhf(c1);

        out[((size_t)b0 * Tt + (t0 + t)) * (Kk * UN) + k * UN + u] = hn0;
        out[((size_t)b1 * Tt + (t0 + t)) * (Kk * UN) + k * UN + u] = hn1;

        __syncthreads();           // everyone done reading old h
        h0s[u] = hn0;
        h1s[u] = hn1;
        __syncthreads();           // new h visible
    }

    hst[p0 * UN + u] = h0s[u];
    hst[p1 * UN + u] = h1s[u];
    cst[p0 * UN + u] = c0;
    cst[p1 * UN + u] = c1;
}

extern "C" void kernel_launch(void* const* d_in, const int* in_sizes, int n_in,
                              void* d_out, int out_size, void* d_ws, size_t ws_size,
                              hipStream_t stream) {
    const float* x    = (const float*)d_in[0];
    const float* W    = (const float*)d_in[1];
    const float* U    = (const float*)d_in[2];
    const float* bias = (const float*)d_in[3];
    float* out = (float*)d_out;

    // ws layout: [xw: TC*128*1024 f32][h: 128*256][c: 128*256]
    const size_t state_f = 2u * 128 * 256;
    int TC = 8;
    const int cands[6] = {512, 256, 128, 64, 32, 16};
    for (int ci = 0; ci < 6; ci++) {
        size_t need = ((size_t)cands[ci] * 128 * 1024 + state_f) * sizeof(float);
        if (need <= ws_size) { TC = cands[ci]; break; }
    }

    float* xw  = (float*)d_ws;
    float* hst = xw + (size_t)TC * 128 * 1024;
    float* cst = hst + 128 * 256;

    init_state_kernel<<<dim3(64), dim3(1024), 0, stream>>>(hst, 2 * 128 * 256);

    for (int t0 = 0; t0 < Tt; t0 += TC) {
        xw_gemm<<<dim3(G4 / 128, TC * 16 / 128, Kk), dim3(256), 0, stream>>>(
            x, W, bias, xw, t0);
        lstm_seq<<<dim3(64), dim3(256), 0, stream>>>(xw, U, out, hst, cst, t0, TC);
    }
}

// Round 2
// 2181.876 us; speedup vs baseline: 2.9665x; 2.9665x over previous
//
#include <hip/hip_runtime.h>
#include <cstdint>
#include <cstddef>

#define Tt  512
#define Kk  8
#define NI  256
#define UN  256
#define G4  1024   // 4*UN

typedef unsigned short ushort_t;
typedef __attribute__((ext_vector_type(8))) short short8;
typedef __attribute__((ext_vector_type(4))) float f32x4;

__global__ void zero_ws(unsigned int* p, int n) {
    int stride = gridDim.x * blockDim.x;
    for (int i = blockIdx.x * blockDim.x + threadIdx.x; i < n; i += stride)
        p[i] = 0u;
}

__device__ __forceinline__ ushort_t f2bf(float x) {
    union { float f; unsigned int u; } v; v.f = x;
    unsigned int r = v.u + 0x7FFFu + ((v.u >> 16) & 1u);
    return (ushort_t)(r >> 16);
}

__device__ __forceinline__ float hsig(float z) {
    return fminf(1.0f, fmaxf(0.0f, fmaf(z, 0.2f, 0.5f)));
}

__device__ __forceinline__ float fast_tanh(float x) {
    // 1 - 2/(e^{2x}+1); saturates correctly at +-inf
    float e = __expf(2.0f * x);
    return 1.0f - 2.0f * __builtin_amdgcn_rcpf(e + 1.0f);
}

// ---------------- Phase A: xw[t'][b*8+k][col] = bias + x@W ----------------
__global__ __launch_bounds__(256) void xw_gemm(const float* __restrict__ x,
                                               const float* __restrict__ W,
                                               const float* __restrict__ bias,
                                               float* __restrict__ xw, int t0) {
    __shared__ __align__(16) float At[16][132];
    __shared__ __align__(16) float Bt[16][132];

    const int k  = blockIdx.z;
    const int C0 = blockIdx.x * 128;
    const int R0 = blockIdx.y * 128;
    const int tid = threadIdx.x;
    const int tx = tid & 15, ty = tid >> 4;

    float acc[8][8];
#pragma unroll
    for (int i = 0; i < 8; i++)
#pragma unroll
        for (int j = 0; j < 8; j++) acc[i][j] = 0.0f;

    const int lakk = tid & 15, larl = tid >> 4;
    const int lbc  = tid & 127, lbk = tid >> 7;

    for (int kt = 0; kt < NI; kt += 16) {
#pragma unroll
        for (int ps = 0; ps < 8; ps++) {
            int rloc = larl + ps * 16;
            int r = R0 + rloc;
            int b = r & 15, tp = r >> 4;
            At[lakk][rloc] = x[(((size_t)b * Tt + (t0 + tp)) * Kk + k) * NI + kt + lakk];
        }
#pragma unroll
        for (int ps = 0; ps < 8; ps++) {
            int kkr = lbk + ps * 2;
            Bt[kkr][lbc] = W[((size_t)k * NI + kt + kkr) * G4 + C0 + lbc];
        }
        __syncthreads();
#pragma unroll
        for (int kk = 0; kk < 16; kk++) {
            const float4* Ar = (const float4*)&At[kk][ty * 8];
            const float4* Br = (const float4*)&Bt[kk][tx * 8];
            float4 a0 = Ar[0], a1 = Ar[1];
            float4 b0 = Br[0], b1 = Br[1];
            float a[8] = {a0.x, a0.y, a0.z, a0.w, a1.x, a1.y, a1.z, a1.w};
            float bb[8] = {b0.x, b0.y, b0.z, b0.w, b1.x, b1.y, b1.z, b1.w};
#pragma unroll
            for (int i = 0; i < 8; i++)
#pragma unroll
                for (int j = 0; j < 8; j++)
                    acc[i][j] = fmaf(a[i], bb[j], acc[i][j]);
        }
        __syncthreads();
    }
    float bv[8];
#pragma unroll
    for (int j = 0; j < 8; j++) bv[j] = bias[(size_t)k * G4 + C0 + tx * 8 + j];
#pragma unroll
    for (int i = 0; i < 8; i++) {
        int r = R0 + ty * 8 + i;
        int b = r & 15, tp = r >> 4;
        float* op = xw + ((size_t)tp * 128 + b * 8 + k) * G4 + C0 + tx * 8;
#pragma unroll
        for (int j = 0; j < 8; j++) op[j] = acc[i][j] + bv[j];
    }
}

// ---------------- Phase B: MFMA recurrence, U resident in VGPRs ----------------
// 32 wgs: k = bid&7, uq = bid>>3. wg owns units [uq*64, uq*64+64) of all 4 gates,
// all 16 batches. wave w handles gate w. B-frags (U slice, bf16) preloaded into
// 128 VGPRs/lane; h exchanged among the 4 wgs of k via L2 + release/acquire flag.
__global__ __launch_bounds__(256, 1) void lstm_mfma(
    const float* __restrict__ xw,        // [TC][128][1024]
    const float* __restrict__ U,         // [8][256][1024] fp32
    float* __restrict__ out,             // [16][512][8][256]
    ushort_t* __restrict__ hstate,       // [8][4096] bf16  (e = uq*1024 + b*64 + u)
    float* __restrict__ cstate,          // [8*4][1024]
    ushort_t* __restrict__ hbuf,         // [2][8][4096] bf16
    int* __restrict__ arrive,            // [8][512]
    int t0, int TC) {
    const int tid  = threadIdx.x;
    const int lane = tid & 63;
    const int w    = tid >> 6;        // wave index = gate (0=a,1=i,2=f,3=o)
    const int k    = blockIdx.x & 7;
    const int uq   = blockIdx.x >> 3;
    const int l15  = lane & 15, quad = lane >> 4;

    __shared__ ushort_t hfr[8 * 64 * 8];      // A-fragment layout: [q][lane][j]
    __shared__ float gact[4][16][65];          // [gate][b][u], pad 65

    // ---- one-time: preload B-fragments of U slice (bf16) ----
    short8 bfr[4][8];
    const int colw = w * 256 + uq * 64;
    const size_t Ubase = (size_t)k * (256 * 1024);
#pragma unroll
    for (int c = 0; c < 4; c++) {
        const int col = colw + c * 16 + l15;
#pragma unroll
        for (int q = 0; q < 8; q++) {
            short8 v;
#pragma unroll
            for (int j = 0; j < 8; j++) {
                int kk = q * 32 + quad * 8 + j;
                v[j] = (short)f2bf(U[Ubase + (size_t)kk * 1024 + col]);
            }
            bfr[c][q] = v;
        }
    }

    // c-state: thread owns (b = bq*4+r, u = tid&63)
    const int uu = tid & 63;
    const int bq = tid >> 6;
    float cc[4];
    const size_t cbase = ((size_t)(k * 4 + uq)) * 1024 + (size_t)tid * 4;
#pragma unroll
    for (int r = 0; r < 4; r++) cc[r] = cstate[cbase + r];

    // ---- initial h scatter: hstate[k] -> A-frag LDS ----
    {
        const ushort_t* src = hstate + (size_t)k * 4096;
#pragma unroll
        for (int i = 0; i < 16; i++) {
            int e = tid + 256 * i;
            int b = (e >> 6) & 15;
            int u = e & 63;
            int kkg = (e >> 10) * 64 + u;
            int q = kkg >> 5, ln = b + 16 * ((kkg & 31) >> 3), j = kkg & 7;
            hfr[(q * 64 + ln) * 8 + j] = src[e];
        }
    }
    __syncthreads();

    // prefetch xw for t=0
    float xwv[4][4];
#pragma unroll
    for (int c = 0; c < 4; c++) {
        int col = colw + c * 16 + l15;
#pragma unroll
        for (int r = 0; r < 4; r++) {
            int b = quad * 4 + r;
            xwv[c][r] = xw[((size_t)0 * 128 + b * 8 + k) * 1024 + col];
        }
    }

#pragma unroll 1
    for (int t = 0; t < TC; t++) {
        const int g = t0 + t;

        // ---- z_hU = h @ Uslice via MFMA ----
        f32x4 acc[4];
        const f32x4 zv = {0.f, 0.f, 0.f, 0.f};
#pragma unroll
        for (int c = 0; c < 4; c++) acc[c] = zv;
#pragma unroll
        for (int q = 0; q < 8; q++) {
            short8 af = *(const short8*)&hfr[(q * 64 + lane) * 8];
#pragma unroll
            for (int c = 0; c < 4; c++)
                acc[c] = __builtin_amdgcn_mfma_f32_16x16x32_bf16(af, bfr[c][q], acc[c], 0, 0, 0);
        }

        // prefetch xw for t+1 (independent of h -> hides L2/HBM latency)
        float xwn[4][4];
        if (t + 1 < TC) {
#pragma unroll
            for (int c = 0; c < 4; c++) {
                int col = colw + c * 16 + l15;
#pragma unroll
                for (int r = 0; r < 4; r++) {
                    int b = quad * 4 + r;
                    xwn[c][r] = xw[((size_t)(t + 1) * 128 + b * 8 + k) * 1024 + col];
                }
            }
        }

        // ---- gate activation (wave w = gate w), write to LDS ----
#pragma unroll
        for (int c = 0; c < 4; c++) {
#pragma unroll
            for (int r = 0; r < 4; r++) {
                float z = acc[c][r] + xwv[c][r];
                float a = (w == 0) ? fast_tanh(z) : hsig(z);
                gact[w][quad * 4 + r][c * 16 + l15] = a;
            }
        }
        __syncthreads();

        // ---- c/h update (thread t: b = bq*4+r, u = uu) ----
        float hn[4];
#pragma unroll
        for (int r = 0; r < 4; r++) {
            int b = bq * 4 + r;
            float av = gact[0][b][uu], iv = gact[1][b][uu];
            float fv = gact[2][b][uu], ov = gact[3][b][uu];
            float cn = av * iv + fv * cc[r];
            cc[r] = cn;
            hn[r] = ov * fast_tanh(cn);
            out[(((size_t)b * Tt + g) * Kk + k) * UN + uq * 64 + uu] = hn[r];
        }

        if (t + 1 < TC) {
            // publish own h slice (bf16) to hbuf[parity]
            ushort_t* dst = hbuf + ((size_t)((g + 1) & 1) * 8 + k) * 4096 + uq * 1024;
#pragma unroll
            for (int r = 0; r < 4; r++)
                dst[(bq * 4 + r) * 64 + uu] = f2bf(hn[r]);
            __syncthreads();   // drains stores (vmcnt 0) for all wg threads
            if (tid == 0) {
                int* flag = arrive + k * 512 + (g + 1);
                __hip_atomic_fetch_add(flag, 1, __ATOMIC_RELEASE, __HIP_MEMORY_SCOPE_AGENT);
                while (__hip_atomic_load(flag, __ATOMIC_ACQUIRE, __HIP_MEMORY_SCOPE_AGENT) < 4) {}
            }
            __syncthreads();
            // scatter full h_{t+1} from hbuf -> A-frag LDS
            const ushort_t* src = hbuf + ((size_t)((g + 1) & 1) * 8 + k) * 4096;
#pragma unroll
            for (int i = 0; i < 16; i++) {
                int e = tid + 256 * i;
                int b = (e >> 6) & 15;
                int u = e & 63;
                int kkg = (e >> 10) * 64 + u;
                int q = kkg >> 5, ln = b + 16 * ((kkg & 31) >> 3), j = kkg & 7;
                hfr[(q * 64 + ln) * 8 + j] = src[e];
            }
            __syncthreads();
#pragma unroll
            for (int c = 0; c < 4; c++)
#pragma unroll
                for (int r = 0; r < 4; r++) xwv[c][r] = xwn[c][r];
        } else {
            // chunk end: persist state
            ushort_t* dst = hstate + (size_t)k * 4096 + uq * 1024;
#pragma unroll
            for (int r = 0; r < 4; r++)
                dst[(bq * 4 + r) * 64 + uu] = f2bf(hn[r]);
#pragma unroll
            for (int r = 0; r < 4; r++) cstate[cbase + r] = cc[r];
        }
    }
}

extern "C" void kernel_launch(void* const* d_in, const int* in_sizes, int n_in,
                              void* d_out, int out_size, void* d_ws, size_t ws_size,
                              hipStream_t stream) {
    const float* x    = (const float*)d_in[0];
    const float* W    = (const float*)d_in[1];
    const float* U    = (const float*)d_in[2];
    const float* bias = (const float*)d_in[3];
    float* out = (float*)d_out;

    // tail state: cstate 128KB | hstate 64KB | hbuf 128KB | arrive 16KB
    const size_t TAIL = 131072 + 65536 + 131072 + 16384;  // 344064 B
    int TC = 16;
    const int cands[6] = {512, 256, 128, 64, 32, 16};
    for (int ci = 0; ci < 6; ci++) {
        size_t need = (size_t)cands[ci] * 128 * 1024 * 4 + TAIL;
        if (need <= ws_size) { TC = cands[ci]; break; }
    }

    float* xw = (float*)d_ws;
    char* p = (char*)d_ws + (size_t)TC * 128 * 1024 * 4;
    float*    cstate = (float*)p;     p += 131072;
    ushort_t* hstate = (ushort_t*)p;  p += 65536;
    ushort_t* hbuf   = (ushort_t*)p;  p += 131072;
    int*      arrive = (int*)p;

    zero_ws<<<dim3(128), dim3(256), 0, stream>>>((unsigned int*)cstate,
                                                 (int)(TAIL / 4));

    for (int t0 = 0; t0 < Tt; t0 += TC) {
        xw_gemm<<<dim3(G4 / 128, TC * 16 / 128, Kk), dim3(256), 0, stream>>>(
            x, W, bias, xw, t0);
        lstm_mfma<<<dim3(32), dim3(256), 0, stream>>>(
            xw, U, out, hstate, cstate, hbuf, arrive, t0, TC);
    }
}